// Round 4
// baseline (671.827 us; speedup 1.0000x reference)
//
#include <hip/hip_runtime.h>

#define D 128
#define NUM_GRAPHS 4096

typedef float v4f __attribute__((ext_vector_type(4)));

__device__ __forceinline__ float dot4(v4f h, v4f w) {
    return h.x * w.x + h.y * w.y + h.z * w.z + h.w * w.w;
}

// Flush per-lane accumulator. cur_g is per-lane (uniform within each 32-lane
// half) so boundaries need no divergent control flow.
__device__ __forceinline__ void flushv(float* __restrict__ S, float* __restrict__ Z,
                                       int cur_g, int colbase, bool zlane,
                                       v4f& acc, float& zacc) {
    float* p = &S[(size_t)cur_g * D + colbase];
    atomicAdd(p + 0, acc.x);
    atomicAdd(p + 1, acc.y);
    atomicAdd(p + 2, acc.z);
    atomicAdd(p + 3, acc.w);
    if (zlane) atomicAdd(&Z[cur_g], zacc);
    acc = (v4f)(0.f);
    zacc = 0.f;
}

// Layout: lane l loads float4; one 1KB wave-load covers TWO rows
//   (lanes 0..31 = row v, lanes 32..63 = row v+1; rows contiguous in memory).
// Quad = 4 loads = 8 rows. Depth-1 branchless clamped prefetch.
// Graph-membership fast path: batch sorted => batch[v+7]==cur_g implies all
// 8 rows belong to cur_g -> ONE probe load per quad instead of 4.
__global__ __launch_bounds__(256) void attn_agg_accum(
    const float* __restrict__ H, const int* __restrict__ batch,
    const float* __restrict__ w, const float* __restrict__ b,
    float* __restrict__ S /* [NUM_GRAPHS*D] = d_out */,
    float* __restrict__ Z /* [NUM_GRAPHS] */,
    int V)
{
    const int lane    = threadIdx.x & 63;
    const int half    = lane >> 5;
    const int colbase = (lane & 31) << 2;
    const bool zlane  = (lane & 31) == 0;

    const int wave_id     = blockIdx.x * (blockDim.x >> 6) + (threadIdx.x >> 6);
    const int total_waves = gridDim.x * (blockDim.x >> 6);
    const int rpw = ((V + total_waves * 8 - 1) / (total_waves * 8)) * 8; // 64

    int row0 = wave_id * rpw;
    if (row0 >= V) return;
    int row1 = row0 + rpw;
    if (row1 > V) row1 = V;
    const int nq = (row1 - row0) >> 3;

    const v4f w4     = ((const v4f*)w)[lane & 31];
    const float bias = b[0];
    const v4f* __restrict__ Hp = (const v4f*)H;

    v4f acc   = (v4f)(0.f);
    float zacc = 0.f;
    int cur_g = batch[row0 + half];

    int v = row0;
    if (nq > 0) {
        const v4f* hp = Hp + (size_t)row0 * 32 + lane;
        v4f h0 = __builtin_nontemporal_load(hp + 0);
        v4f h1 = __builtin_nontemporal_load(hp + 64);
        v4f h2 = __builtin_nontemporal_load(hp + 128);
        v4f h3 = __builtin_nontemporal_load(hp + 192);
        int s  = batch[row0 + 7];

        for (int q = 0; q < nq; ++q) {
            v = row0 + q * 8;
            const int pv = min(v + 8, row1 - 8);     // branchless clamp
            const v4f* np = Hp + (size_t)pv * 32 + lane;
            v4f n0 = __builtin_nontemporal_load(np + 0);
            v4f n1 = __builtin_nontemporal_load(np + 64);
            v4f n2 = __builtin_nontemporal_load(np + 128);
            v4f n3 = __builtin_nontemporal_load(np + 192);
            const int ns = batch[pv + 7];

            float d0 = dot4(h0, w4);
            float d1 = dot4(h1, w4);
            float d2 = dot4(h2, w4);
            float d3 = dot4(h3, w4);
            #pragma unroll
            for (int off = 16; off > 0; off >>= 1) { // stays within half-wave
                d0 += __shfl_xor(d0, off, 64);
                d1 += __shfl_xor(d1, off, 64);
                d2 += __shfl_xor(d2, off, 64);
                d3 += __shfl_xor(d3, off, 64);
            }

            const float l0 = __expf(d0 + bias);
            const float l1 = __expf(d1 + bias);
            const float l2 = __expf(d2 + bias);
            const float l3 = __expf(d3 + bias);

            if (!__any(s != cur_g)) {                // all 8 rows in cur_g
                acc += h0 * l0 + h1 * l1 + h2 * l2 + h3 * l3;
                zacc += l0 + l1 + l2 + l3;
            } else {                                 // boundary quad (rare)
                int g0 = batch[v + 0 + half];
                int g1 = batch[v + 2 + half];
                int g2 = batch[v + 4 + half];
                int g3 = batch[v + 6 + half];
                if (__any(g0 != cur_g)) { flushv(S, Z, cur_g, colbase, zlane, acc, zacc); cur_g = g0; }
                acc += h0 * l0; zacc += l0;
                if (__any(g1 != cur_g)) { flushv(S, Z, cur_g, colbase, zlane, acc, zacc); cur_g = g1; }
                acc += h1 * l1; zacc += l1;
                if (__any(g2 != cur_g)) { flushv(S, Z, cur_g, colbase, zlane, acc, zacc); cur_g = g2; }
                acc += h2 * l2; zacc += l2;
                if (__any(g3 != cur_g)) { flushv(S, Z, cur_g, colbase, zlane, acc, zacc); cur_g = g3; }
                acc += h3 * l3; zacc += l3;
            }

            h0 = n0; h1 = n1; h2 = n2; h3 = n3; s = ns;
        }
        v = row0 + nq * 8;
    }

    // pair remainder (none for V=1e6 with this grid, kept for generality)
    for (; v + 2 <= row1; v += 2) {
        v4f h = __builtin_nontemporal_load(Hp + (size_t)v * 32 + lane);
        int g = batch[v + half];
        float d = dot4(h, w4);
        #pragma unroll
        for (int off = 16; off > 0; off >>= 1)
            d += __shfl_xor(d, off, 64);
        const float l = __expf(d + bias);
        if (__any(g != cur_g)) { flushv(S, Z, cur_g, colbase, zlane, acc, zacc); cur_g = g; }
        acc += h * l; zacc += l;
    }

    flushv(S, Z, cur_g, colbase, zlane, acc, zacc);
}

__global__ __launch_bounds__(256) void attn_agg_norm(
    float* __restrict__ out, const float* __restrict__ Z, int n)
{
    const int i = blockIdx.x * blockDim.x + threadIdx.x;
    if (i < n) {
        const int g = i >> 7;            // D == 128
        out[i] = out[i] / Z[g];
    }
}

extern "C" void kernel_launch(void* const* d_in, const int* in_sizes, int n_in,
                              void* d_out, int out_size, void* d_ws, size_t ws_size,
                              hipStream_t stream) {
    const float* H     = (const float*)d_in[0];
    const int*   batch = (const int*)  d_in[1];
    const float* w     = (const float*)d_in[2];
    const float* b     = (const float*)d_in[3];
    float* out = (float*)d_out;          // [NUM_GRAPHS, D] accumulator + result
    float* Z   = (float*)d_ws;           // [NUM_GRAPHS]

    const int V = in_sizes[0] / D;       // 1,000,000

    hipMemsetAsync(out, 0, (size_t)out_size * sizeof(float), stream);
    hipMemsetAsync(Z,   0, NUM_GRAPHS * sizeof(float), stream);

    // 4096 blocks x 256 = 16384 waves; 64 rows/wave (V = 15625*64, zero tail)
    attn_agg_accum<<<4096, 256, 0, stream>>>(H, batch, w, b, out, Z, V);

    const int n = NUM_GRAPHS * D;
    attn_agg_norm<<<(n + 255) / 256, 256, 0, stream>>>(out, Z, n);
}